// Round 5
// baseline (492.731 us; speedup 1.0000x reference)
//
#include <hip/hip_runtime.h>

#define NN 50000
#define NE 800000
#define HID 128
#define NB 32
#define SCAN_B 196   // 196*256 = 50176 >= NN
#define NPB 16       // dst nodes per edge block
#define ET 64        // edges per tile

typedef short short8 __attribute__((ext_vector_type(8)));
typedef float f32x4 __attribute__((ext_vector_type(4)));

static __device__ __forceinline__ short f2bf(float x) {
    unsigned int u = __float_as_uint(x);
    unsigned int r = (u + 0x7fffu + ((u >> 16) & 1u)) >> 16;
    return (short)r;
}
static __device__ __forceinline__ float bf2f(unsigned short s) {
    return __uint_as_float(((unsigned int)s) << 16);
}

// ---- prep: dst histogram (blocks < 3125) + weight transposes ----
__global__ void fused_prep(const int* __restrict__ dstI, int* __restrict__ counts,
                           const float* __restrict__ W1, const float* __restrict__ W2,
                           const float* __restrict__ Wo,
                           short* __restrict__ W1aT, short* __restrict__ W1bT,
                           short* __restrict__ W1cT, short* __restrict__ W2t,
                           short* __restrict__ Wot) {
    int b = blockIdx.x;
    if (b < 3125) {
        int e = b * 256 + threadIdx.x;
        atomicAdd(&counts[dstI[e]], 1);
    } else {
        int t = (b - 3125) * 256 + threadIdx.x;   // 0..69631
        if (t < 16384) {
            int n = t >> 7, k = t & 127;
            W1aT[t] = f2bf(W1[k * HID + n]);
        } else if ((t -= 16384) < 16384) {
            int n = t >> 7, k = t & 127;
            W1bT[t] = f2bf(W1[(k + 128) * HID + n]);
        } else if ((t -= 16384) < 4096) {
            int n = t >> 5, k = t & 31;
            W1cT[t] = f2bf(W1[(k + 256) * HID + n]);
        } else if ((t -= 4096) < 16384) {
            int n = t >> 7, k = t & 127;
            W2t[t] = f2bf(W2[k * HID + n]);
        } else if ((t -= 16384) < 16384) {
            int n = t >> 7, k = t & 127;
            Wot[t] = f2bf(Wo[k * HID + n]);
        }
    }
}

// ---- scan stage 1: per-block exclusive scan + block sums ----
__global__ void k_scan1(const int* __restrict__ counts, int* __restrict__ scanEx,
                        int* __restrict__ blockSum) {
    __shared__ int s[256];
    int t = threadIdx.x, idx = blockIdx.x * 256 + t;
    int v = counts[idx];   // counts sized 50176, zeroed
    s[t] = v; __syncthreads();
    #pragma unroll
    for (int off = 1; off < 256; off <<= 1) {
        int x = (t >= off) ? s[t - off] : 0;
        __syncthreads();
        s[t] += x;
        __syncthreads();
    }
    scanEx[idx] = s[t] - v;
    if (t == 255) blockSum[blockIdx.x] = s[255];
}

// ---- scan stage 2+3 fused: nodeBase = scanEx + sum(blockSum[0..b)); cur = same ----
__global__ void k_scan23(const int* __restrict__ scanEx, const int* __restrict__ blockSum,
                         int* __restrict__ nodeBase, int* __restrict__ cur) {
    __shared__ int s[256];
    int t = threadIdx.x, b = blockIdx.x;
    s[t] = (t < b) ? blockSum[t] : 0;
    __syncthreads();
    #pragma unroll
    for (int off = 128; off > 0; off >>= 1) {
        if (t < off) s[t] += s[t + off];
        __syncthreads();
    }
    int idx = b * 256 + t;
    int val = scanEx[idx] + s[0];
    nodeBase[idx] = val;   // note: counts[NN..] == 0 -> nodeBase[NN] == NE automatically
    cur[idx] = val;
}

__global__ void k_permute(const int* __restrict__ src, const int* __restrict__ dst,
                          int* __restrict__ cur, int2* __restrict__ edgeS) {
    int e = blockIdx.x * 256 + threadIdx.x;
    int s = src[e];
    int d = dst[e];
    int r = atomicAdd(&cur[d], 1);
    edgeS[r] = make_int2(s, d);
}

// ---- per-node precompute: S = nf@W1a, D = nf@W1b (bf16 out) ----
__global__ void sd_kernel(const float* __restrict__ nf,
                          const short* __restrict__ W1aT, const short* __restrict__ W1bT,
                          short* __restrict__ Sg, short* __restrict__ Dg) {
    __shared__ short As[64 * 136];
    const int tid  = threadIdx.x;
    const int wave = tid >> 6;
    const int lane = tid & 63;
    const int quad = lane >> 4;
    const int l15  = lane & 15;
    const int n0   = blockIdx.x * 64;

    {
        int row = tid >> 2, pt = tid & 3;
        int node = min(n0 + row, NN - 1);
        const float4* p = (const float4*)(nf + (size_t)node * HID + pt * 32);
        #pragma unroll
        for (int j = 0; j < 4; ++j) {
            float4 w0 = p[j * 2], w1 = p[j * 2 + 1];
            short8 o;
            o[0] = f2bf(w0.x); o[1] = f2bf(w0.y); o[2] = f2bf(w0.z); o[3] = f2bf(w0.w);
            o[4] = f2bf(w1.x); o[5] = f2bf(w1.y); o[6] = f2bf(w1.z); o[7] = f2bf(w1.w);
            *(short8*)(As + row * 136 + pt * 32 + j * 8) = o;
        }
    }
    __syncthreads();

    f32x4 aS[4][2], aD[4][2];
    #pragma unroll
    for (int mt = 0; mt < 4; ++mt)
        #pragma unroll
        for (int nt = 0; nt < 2; ++nt) {
            aS[mt][nt] = (f32x4){0.f, 0.f, 0.f, 0.f};
            aD[mt][nt] = (f32x4){0.f, 0.f, 0.f, 0.f};
        }

    #pragma unroll
    for (int kk = 0; kk < 4; ++kk) {
        int ko = kk * 32 + quad * 8;
        short8 a[4];
        #pragma unroll
        for (int mt = 0; mt < 4; ++mt)
            a[mt] = *(const short8*)(As + (mt * 16 + l15) * 136 + ko);
        #pragma unroll
        for (int nt = 0; nt < 2; ++nt) {
            int n = wave * 32 + nt * 16 + l15;
            short8 bS = *(const short8*)(W1aT + n * HID + ko);
            short8 bD = *(const short8*)(W1bT + n * HID + ko);
            #pragma unroll
            for (int mt = 0; mt < 4; ++mt) {
                aS[mt][nt] = __builtin_amdgcn_mfma_f32_16x16x32_bf16(a[mt], bS, aS[mt][nt], 0, 0, 0);
                aD[mt][nt] = __builtin_amdgcn_mfma_f32_16x16x32_bf16(a[mt], bD, aD[mt][nt], 0, 0, 0);
            }
        }
    }

    #pragma unroll
    for (int nt = 0; nt < 2; ++nt) {
        int col = wave * 32 + nt * 16 + l15;
        #pragma unroll
        for (int mt = 0; mt < 4; ++mt) {
            #pragma unroll
            for (int r = 0; r < 4; ++r) {
                int node = n0 + mt * 16 + quad * 4 + r;
                if (node < NN) {
                    Sg[(size_t)node * HID + col] = f2bf(aS[mt][nt][r]);
                    Dg[(size_t)node * HID + col] = f2bf(aD[mt][nt][r]);
                }
            }
        }
    }
}

// ---- node-centric fused edge MLP + LDS accumulate + output GEMM ----
// Block owns NPB=16 dst nodes; walks its CSR segment in 64-edge tiles.
// S staged into Ps and consumed in-place by SiLU; D staged once per block.
__launch_bounds__(256, 4)
__global__ void edge_node(const short* __restrict__ Sg,
                          const short* __restrict__ Dg,
                          const float* __restrict__ pos,
                          const int2* __restrict__ edgeS,
                          const int* __restrict__ nodeBase,
                          const int* __restrict__ counts,
                          const short* __restrict__ W1cT,
                          const float* __restrict__ b1,
                          const short* __restrict__ W2t,
                          const float* __restrict__ b2,
                          const short* __restrict__ Wot,
                          const float* __restrict__ bo,
                          float* __restrict__ out) {
    __shared__ float accL[17 * 132];     //  8976 B (row 16 = dump row for padding)
    __shared__ short Ps[ET * 136];       // 17408 B (S stage -> silu in place -> A2 reuse)
    __shared__ short R[ET * 56];         //  7168 B rbf
    __shared__ short Dl[17 * 128];       //  4352 B (row 16 zeroed, for padding reads)
    __shared__ int   dn_sh[ET];
    __shared__ float inv_sh[NPB];

    const int tid  = threadIdx.x;
    const int lane = tid & 63;
    const int nsl  = tid >> 6;        // wave = col slice
    const int quad = lane >> 4;
    const int l15  = lane & 15;
    const int n0   = blockIdx.x * NPB;

    // zero acc, stage D rows (block's own 16 nodes), zero dump D row
    for (int i = tid; i < 17 * 132; i += 256) accL[i] = 0.f;
    {
        int row = tid >> 4, ch = tid & 15;
        *(short8*)(Dl + row * 128 + ch * 8) =
            *(const short8*)(Dg + (size_t)(n0 + row) * HID + ch * 8);
    }
    if (tid < 16) {
        short8 z = (short8){0,0,0,0,0,0,0,0};
        *(short8*)(Dl + 16 * 128 + tid * 8) = z;
    }
    float b1c[2] = { b1[nsl * 32 + l15], b1[nsl * 32 + 16 + l15] };
    float b2c[2] = { b2[nsl * 32 + l15], b2[nsl * 32 + 16 + l15] };

    const int e0 = nodeBase[n0];
    const int e1 = nodeBase[n0 + NPB];
    const unsigned short* Psu = (const unsigned short*)Ps;
    const unsigned short* Dlu = (const unsigned short*)Dl;

    for (int te = e0; te < e1; te += ET) {
        // ---- stage: S rows into Ps, rbf into R, dst-local ids ----
        {
            int es = tid >> 2, pt = tid & 3;
            int e = te + es;
            int valid = (e < e1);
            int ee = valid ? e : (e1 - 1);
            int2 sd = edgeS[ee];
            int s = sd.x, d = sd.y;
            if (pt == 0) dn_sh[es] = valid ? (d - n0) : NPB;
            #pragma unroll
            for (int j = 0; j < 4; ++j)
                *(short8*)(Ps + es * 136 + pt * 32 + j * 8) =
                    *(const short8*)(Sg + (size_t)s * HID + pt * 32 + j * 8);
            float dx = pos[d * 3 + 0] - pos[s * 3 + 0];
            float dy = pos[d * 3 + 1] - pos[s * 3 + 1];
            float dz = pos[d * 3 + 2] - pos[s * 3 + 2];
            float dd = fminf(sqrtf(dx * dx + dy * dy + dz * dz), 5.0f);
            const float step  = 5.0f / 31.0f;
            const float width = 0.5f * (step + 0.01f);
            const float coef  = -0.5f / (width * width);
            short8 r;
            #pragma unroll
            for (int j = 0; j < 8; ++j) {
                float c = step * (float)(pt * 8 + j);
                float t = dd - c;
                r[j] = f2bf(__expf(coef * t * t));
            }
            *(short8*)(R + es * 56 + pt * 8) = r;
        }
        __syncthreads();

        // ---- layer 1: rbf [64x32] @ W1c [32x128] ----
        f32x4 acc[4][2];
        #pragma unroll
        for (int mt = 0; mt < 4; ++mt)
            #pragma unroll
            for (int nt = 0; nt < 2; ++nt) acc[mt][nt] = (f32x4){0.f, 0.f, 0.f, 0.f};
        {
            int ko = quad * 8;
            short8 a[4];
            #pragma unroll
            for (int mt = 0; mt < 4; ++mt)
                a[mt] = *(const short8*)(R + (mt * 16 + l15) * 56 + ko);
            #pragma unroll
            for (int nt = 0; nt < 2; ++nt) {
                int n = nsl * 32 + nt * 16 + l15;
                short8 b = *(const short8*)(W1cT + n * NB + ko);
                #pragma unroll
                for (int mt = 0; mt < 4; ++mt)
                    acc[mt][nt] = __builtin_amdgcn_mfma_f32_16x16x32_bf16(a[mt], b, acc[mt][nt], 0, 0, 0);
            }
        }

        // ---- + S (in Ps) + D + b1, SiLU -> Ps in place ----
        #pragma unroll
        for (int mt = 0; mt < 4; ++mt) {
            #pragma unroll
            for (int r = 0; r < 4; ++r) {
                int row = mt * 16 + quad * 4 + r;
                int dn = dn_sh[row];
                #pragma unroll
                for (int nt = 0; nt < 2; ++nt) {
                    int col = nsl * 32 + nt * 16 + l15;
                    float S = bf2f(Psu[row * 136 + col]);
                    float D = bf2f(Dlu[dn * 128 + col]);
                    float x = acc[mt][nt][r] + S + D + b1c[nt];
                    float p = x * __builtin_amdgcn_rcpf(1.0f + __expf(-x));
                    Ps[row * 136 + col] = f2bf(p);
                }
            }
        }
        __syncthreads();

        // ---- layer 2: [64x128] @ [128x128] ----
        f32x4 acc2[4][2];
        #pragma unroll
        for (int mt = 0; mt < 4; ++mt)
            #pragma unroll
            for (int nt = 0; nt < 2; ++nt) acc2[mt][nt] = (f32x4){0.f, 0.f, 0.f, 0.f};

        #pragma unroll
        for (int kk = 0; kk < 4; ++kk) {
            int ko = kk * 32 + quad * 8;
            short8 a[4];
            #pragma unroll
            for (int mt = 0; mt < 4; ++mt)
                a[mt] = *(const short8*)(Ps + (mt * 16 + l15) * 136 + ko);
            #pragma unroll
            for (int nt = 0; nt < 2; ++nt) {
                int n = nsl * 32 + nt * 16 + l15;
                short8 b = *(const short8*)(W2t + n * HID + ko);
                #pragma unroll
                for (int mt = 0; mt < 4; ++mt)
                    acc2[mt][nt] = __builtin_amdgcn_mfma_f32_16x16x32_bf16(a[mt], b, acc2[mt][nt], 0, 0, 0);
            }
        }

        // ---- run-merged LDS atomic accumulate (rows sorted by dst) ----
        #pragma unroll
        for (int nt = 0; nt < 2; ++nt) {
            int col = nsl * 32 + nt * 16 + l15;
            #pragma unroll
            for (int mt = 0; mt < 4; ++mt) {
                int rbase = mt * 16 + quad * 4;
                int rnode = dn_sh[rbase];
                float run = 0.0f;
                #pragma unroll
                for (int r = 0; r < 4; ++r) {
                    int node = dn_sh[rbase + r];
                    float v = acc2[mt][nt][r] + b2c[nt];
                    if (node != rnode) {
                        atomicAdd(&accL[rnode * 132 + col], run);
                        rnode = node;
                        run = v;
                    } else {
                        run += v;
                    }
                }
                atomicAdd(&accL[rnode * 132 + col], run);
            }
        }
        __syncthreads();
    }
    __syncthreads();   // covers zero-init -> epilogue when segment is empty

    // ---- normalize by degree -> bf16 A-tile (reuse Ps) ----
    if (tid < NPB) inv_sh[tid] = 1.0f / fmaxf((float)counts[n0 + tid], 1.0f);
    __syncthreads();
    {
        int row = tid & 15, j0 = (tid >> 4) * 8;
        float inv = inv_sh[row];
        short8 o;
        #pragma unroll
        for (int j = 0; j < 8; ++j)
            o[j] = f2bf(accL[row * 132 + j0 + j] * inv);
        *(short8*)(Ps + row * 136 + j0) = o;
    }
    __syncthreads();

    // ---- output GEMM: [16x128] @ Wo [128x128] + bo -> out rows n0..n0+15 ----
    f32x4 ao[2];
    ao[0] = (f32x4){0.f, 0.f, 0.f, 0.f};
    ao[1] = (f32x4){0.f, 0.f, 0.f, 0.f};
    #pragma unroll
    for (int kk = 0; kk < 4; ++kk) {
        int ko = kk * 32 + quad * 8;
        short8 a = *(const short8*)(Ps + l15 * 136 + ko);
        #pragma unroll
        for (int nt = 0; nt < 2; ++nt) {
            int n = nsl * 32 + nt * 16 + l15;
            short8 b = *(const short8*)(Wot + n * HID + ko);
            ao[nt] = __builtin_amdgcn_mfma_f32_16x16x32_bf16(a, b, ao[nt], 0, 0, 0);
        }
    }
    #pragma unroll
    for (int nt = 0; nt < 2; ++nt) {
        int col = nsl * 32 + nt * 16 + l15;
        float bias = bo[col];
        #pragma unroll
        for (int r = 0; r < 4; ++r) {
            int row = quad * 4 + r;
            out[(size_t)(n0 + row) * HID + col] = ao[nt][r] + bias;
        }
    }
}

extern "C" void kernel_launch(void* const* d_in, const int* in_sizes, int n_in,
                              void* d_out, int out_size, void* d_ws, size_t ws_size,
                              hipStream_t stream) {
    const float* nf  = (const float*)d_in[0];
    const float* pos = (const float*)d_in[1];
    const int*   ei  = (const int*)d_in[2];
    const float* W1  = (const float*)d_in[3];
    const float* b1  = (const float*)d_in[4];
    const float* W2  = (const float*)d_in[5];
    const float* b2  = (const float*)d_in[6];
    const float* Wo  = (const float*)d_in[7];
    const float* bo  = (const float*)d_in[8];
    float* out = (float*)d_out;

    char* ws = (char*)d_ws;
    short* W1aT     = (short*)(ws);                 //     32,768
    short* W1bT     = (short*)(ws + 32768);         //     32,768
    short* W1cT     = (short*)(ws + 65536);         //      8,192
    short* W2t      = (short*)(ws + 73728);         //     32,768
    short* Wot      = (short*)(ws + 106496);        //     32,768
    int*   counts   = (int*)(ws + 139264);          //    200,704
    int*   nodeBase = (int*)(ws + 339968);          //    200,704
    int*   cur      = (int*)(ws + 540672);          //    200,704
    int*   blockSum = (int*)(ws + 741376);          //      1,024
    int2*  edgeS    = (int2*)(ws + 742400);         //  6,400,000
    short* Sg       = (short*)(ws + 7142400);       // 12,800,000
    short* Dg       = (short*)(ws + 19942400);      // 12,800,000  -> total 32,742,400
    int*   scanEx   = (int*)Sg;   // aliased: dead before sd_kernel writes Sg

    hipMemsetAsync(counts, 0, 200704, stream);

    fused_prep<<<3397, 256, 0, stream>>>(ei + NE, counts, W1, W2, Wo,
                                         W1aT, W1bT, W1cT, W2t, Wot);
    k_scan1<<<SCAN_B, 256, 0, stream>>>(counts, scanEx, blockSum);
    k_scan23<<<SCAN_B, 256, 0, stream>>>(scanEx, blockSum, nodeBase, cur);
    k_permute<<<3125, 256, 0, stream>>>(ei, ei + NE, cur, edgeS);
    sd_kernel<<<(NN + 63) / 64, 256, 0, stream>>>(nf, W1aT, W1bT, Sg, Dg);
    edge_node<<<NN / NPB, 256, 0, stream>>>(Sg, Dg, pos, edgeS, nodeBase, counts,
                                            W1cT, b1, W2t, b2, Wot, bo, out);
}

// Round 7
// 332.307 us; speedup vs baseline: 1.4828x; 1.4828x over previous
//
#include <hip/hip_runtime.h>
#include <hip/hip_bf16.h>

#define NN 50000
#define NE 800000
#define HID 128
#define NB 32
#define SCAN_B 196   // 196*256 = 50176 >= NN

typedef short short8 __attribute__((ext_vector_type(8)));
typedef float f32x4 __attribute__((ext_vector_type(4)));

static __device__ __forceinline__ short f2bf(float x) {
    union { __hip_bfloat16 h; short s; } r;
    r.h = __float2bfloat16(x);       // HW RNE cvt
    return r.s;
}
static __device__ __forceinline__ float bf2f(unsigned short s) {
    return __uint_as_float(((unsigned int)s) << 16);
}
// packed bf16 add (HW packed add on gfx950)
static __device__ __forceinline__ unsigned int addpack(unsigned int a, unsigned int b) {
    union { unsigned int u; __hip_bfloat162 h; } x, y, r;
    x.u = a; y.u = b;
    r.h = __hadd2(x.h, y.h);
    return r.u;
}

// ---- prep: dst histogram (blocks < 3125) + weight transposes ----
__global__ void fused_prep(const int* __restrict__ dstI, int* __restrict__ counts,
                           const float* __restrict__ W1, const float* __restrict__ W2,
                           const float* __restrict__ Wo,
                           short* __restrict__ W1aT, short* __restrict__ W1bT,
                           short* __restrict__ W1cT, short* __restrict__ W2t,
                           short* __restrict__ Wot) {
    int b = blockIdx.x;
    if (b < 3125) {
        int e = b * 256 + threadIdx.x;
        atomicAdd(&counts[dstI[e]], 1);
    } else {
        int t = (b - 3125) * 256 + threadIdx.x;   // 0..69631
        if (t < 16384) {
            int n = t >> 7, k = t & 127;
            W1aT[t] = f2bf(W1[k * HID + n]);
        } else if ((t -= 16384) < 16384) {
            int n = t >> 7, k = t & 127;
            W1bT[t] = f2bf(W1[(k + 128) * HID + n]);
        } else if ((t -= 16384) < 4096) {
            int n = t >> 5, k = t & 31;
            W1cT[t] = f2bf(W1[(k + 256) * HID + n]);
        } else if ((t -= 4096) < 16384) {
            int n = t >> 7, k = t & 127;
            W2t[t] = f2bf(W2[k * HID + n]);
        } else if ((t -= 16384) < 16384) {
            int n = t >> 7, k = t & 127;
            Wot[t] = f2bf(Wo[k * HID + n]);
        }
    }
}

// ---- scan stage 1 ----
__global__ void k_scan1(const int* __restrict__ counts, int* __restrict__ scanEx,
                        int* __restrict__ blockSum) {
    __shared__ int s[256];
    int t = threadIdx.x, idx = blockIdx.x * 256 + t;
    int v = counts[idx];   // counts sized 50176, zeroed
    s[t] = v; __syncthreads();
    #pragma unroll
    for (int off = 1; off < 256; off <<= 1) {
        int x = (t >= off) ? s[t - off] : 0;
        __syncthreads();
        s[t] += x;
        __syncthreads();
    }
    scanEx[idx] = s[t] - v;
    if (t == 255) blockSum[blockIdx.x] = s[255];
}

// ---- scan stage 2+3 fused: cur = scanEx + sum(blockSum[0..b)) ----
__global__ void k_scan23(const int* __restrict__ scanEx, const int* __restrict__ blockSum,
                         int* __restrict__ cur) {
    __shared__ int s[256];
    int t = threadIdx.x, b = blockIdx.x;
    s[t] = (t < b) ? blockSum[t] : 0;
    __syncthreads();
    #pragma unroll
    for (int off = 128; off > 0; off >>= 1) {
        if (t < off) s[t] += s[t + off];
        __syncthreads();
    }
    int idx = b * 256 + t;
    cur[idx] = scanEx[idx] + s[0];
}

// ---- permute: write 4B original-edge index into sorted position ----
__global__ void k_permute(const int* __restrict__ dst,
                          int* __restrict__ cur, int* __restrict__ perm) {
    int e = blockIdx.x * 256 + threadIdx.x;
    int d = dst[e];
    int r = atomicAdd(&cur[d], 1);
    perm[r] = e;
}

// ---- per-node precompute: S = nf@W1a, D = nf@W1b (bf16 out) ----
__global__ void sd_kernel(const float* __restrict__ nf,
                          const short* __restrict__ W1aT, const short* __restrict__ W1bT,
                          short* __restrict__ Sg, short* __restrict__ Dg) {
    __shared__ short As[64 * 136];
    const int tid  = threadIdx.x;
    const int wave = tid >> 6;
    const int lane = tid & 63;
    const int quad = lane >> 4;
    const int l15  = lane & 15;
    const int n0   = blockIdx.x * 64;

    {
        int row = tid >> 2, pt = tid & 3;
        int node = min(n0 + row, NN - 1);
        const float4* p = (const float4*)(nf + (size_t)node * HID + pt * 32);
        #pragma unroll
        for (int j = 0; j < 4; ++j) {
            float4 w0 = p[j * 2], w1 = p[j * 2 + 1];
            short8 o;
            o[0] = f2bf(w0.x); o[1] = f2bf(w0.y); o[2] = f2bf(w0.z); o[3] = f2bf(w0.w);
            o[4] = f2bf(w1.x); o[5] = f2bf(w1.y); o[6] = f2bf(w1.z); o[7] = f2bf(w1.w);
            *(short8*)(As + row * 136 + pt * 32 + j * 8) = o;
        }
    }
    __syncthreads();

    f32x4 aS[4][2], aD[4][2];
    #pragma unroll
    for (int mt = 0; mt < 4; ++mt)
        #pragma unroll
        for (int nt = 0; nt < 2; ++nt) {
            aS[mt][nt] = (f32x4){0.f, 0.f, 0.f, 0.f};
            aD[mt][nt] = (f32x4){0.f, 0.f, 0.f, 0.f};
        }

    #pragma unroll
    for (int kk = 0; kk < 4; ++kk) {
        int ko = kk * 32 + quad * 8;
        short8 a[4];
        #pragma unroll
        for (int mt = 0; mt < 4; ++mt)
            a[mt] = *(const short8*)(As + (mt * 16 + l15) * 136 + ko);
        #pragma unroll
        for (int nt = 0; nt < 2; ++nt) {
            int n = wave * 32 + nt * 16 + l15;
            short8 bS = *(const short8*)(W1aT + n * HID + ko);
            short8 bD = *(const short8*)(W1bT + n * HID + ko);
            #pragma unroll
            for (int mt = 0; mt < 4; ++mt) {
                aS[mt][nt] = __builtin_amdgcn_mfma_f32_16x16x32_bf16(a[mt], bS, aS[mt][nt], 0, 0, 0);
                aD[mt][nt] = __builtin_amdgcn_mfma_f32_16x16x32_bf16(a[mt], bD, aD[mt][nt], 0, 0, 0);
            }
        }
    }

    #pragma unroll
    for (int nt = 0; nt < 2; ++nt) {
        int col = wave * 32 + nt * 16 + l15;
        #pragma unroll
        for (int mt = 0; mt < 4; ++mt) {
            #pragma unroll
            for (int r = 0; r < 4; ++r) {
                int node = n0 + mt * 16 + quad * 4 + r;
                if (node < NN) {
                    Sg[(size_t)node * HID + col] = f2bf(aS[mt][nt][r]);
                    Dg[(size_t)node * HID + col] = f2bf(aD[mt][nt][r]);
                }
            }
        }
    }
}

// ---- fused edge MLP + tile-merged scatter (edges sorted by dst via perm) ----
// 128 edges/block, 512 threads. Layer1 = rbf@W1c (K=32) + gathered PRE=S[src]+D[dst].
__launch_bounds__(512, 6)
__global__ void edge_kernel(const short* __restrict__ Sg,
                            const short* __restrict__ Dg,
                            const float* __restrict__ pos,
                            const int* __restrict__ perm,
                            const int* __restrict__ srcI,
                            const int* __restrict__ dstI,
                            const short* __restrict__ W1cT,
                            const float* __restrict__ b1,
                            const short* __restrict__ W2t,
                            const float* __restrict__ b2,
                            float* __restrict__ upd) {
    __shared__ char buf[49152];
    __shared__ int  dn_sh[128];
    short* PRE = (short*)buf;              // [128][136] bf16: S[src]+D[dst]
    short* R   = (short*)(buf + 34816);    // [128][56]  bf16 rbf
    short* Ps  = (short*)buf;              // [128][136] (in-place after PRE consumed)
    float* UfT = (float*)buf;              // [128 cols][68] fp32, one 64-row half

    const int tid  = threadIdx.x;
    const int wave = tid >> 6;
    const int lane = tid & 63;
    const int quad = lane >> 4;
    const int l15  = lane & 15;
    const int mg   = wave >> 2;       // row half: [mg*64, mg*64+64)
    const int nsl  = wave & 3;        // col slice: [nsl*32, nsl*32+32)
    const int e0   = blockIdx.x * 128;

    // ---- stage: PRE = S[src]+D[dst] (packed bf16 HW add), RBF tile, dst ids ----
    {
        int es = tid >> 2, pt = tid & 3;
        int pe = perm[e0 + es];
        int s = srcI[pe], d = dstI[pe];
        const int4* sp = (const int4*)(Sg + (size_t)s * HID + pt * 32);
        const int4* dp = (const int4*)(Dg + (size_t)d * HID + pt * 32);
        int4* op = (int4*)(PRE + es * 136 + pt * 32);
        #pragma unroll
        for (int j = 0; j < 4; ++j) {
            int4 a = sp[j], b = dp[j];
            int4 o;
            o.x = addpack(a.x, b.x);
            o.y = addpack(a.y, b.y);
            o.z = addpack(a.z, b.z);
            o.w = addpack(a.w, b.w);
            op[j] = o;
        }
        if (pt == 0) dn_sh[es] = d;
        float dx = pos[d * 3 + 0] - pos[s * 3 + 0];
        float dy = pos[d * 3 + 1] - pos[s * 3 + 1];
        float dz = pos[d * 3 + 2] - pos[s * 3 + 2];
        float dd = fminf(sqrtf(dx * dx + dy * dy + dz * dz), 5.0f);
        const float step  = 5.0f / 31.0f;
        const float width = 0.5f * (step + 0.01f);
        const float coef  = -0.5f / (width * width);
        short8 r;
        #pragma unroll
        for (int j = 0; j < 8; ++j) {
            float c = step * (float)(pt * 8 + j);
            float t = dd - c;
            r[j] = f2bf(__expf(coef * t * t));
        }
        *(short8*)(R + es * 56 + pt * 8) = r;
    }
    __syncthreads();

    // ---- layer 1: rbf [128x32] @ W1c [32x128], single K-step ----
    f32x4 acc[4][2];
    #pragma unroll
    for (int mt = 0; mt < 4; ++mt)
        #pragma unroll
        for (int nt = 0; nt < 2; ++nt) acc[mt][nt] = (f32x4){0.f, 0.f, 0.f, 0.f};
    {
        int ko = quad * 8;
        short8 a[4];
        #pragma unroll
        for (int mt = 0; mt < 4; ++mt)
            a[mt] = *(const short8*)(R + (mg * 64 + mt * 16 + l15) * 56 + ko);
        #pragma unroll
        for (int nt = 0; nt < 2; ++nt) {
            int n = nsl * 32 + nt * 16 + l15;
            short8 b = *(const short8*)(W1cT + n * NB + ko);
            #pragma unroll
            for (int mt = 0; mt < 4; ++mt)
                acc[mt][nt] = __builtin_amdgcn_mfma_f32_16x16x32_bf16(a[mt], b, acc[mt][nt], 0, 0, 0);
        }
    }

    // ---- + PRE + b1, SiLU -> Ps in place ----
    {
        float b1c[2] = { b1[nsl * 32 + l15], b1[nsl * 32 + 16 + l15] };
        const unsigned short* PREu = (const unsigned short*)PRE;
        #pragma unroll
        for (int nt = 0; nt < 2; ++nt) {
            int col = nsl * 32 + nt * 16 + l15;
            #pragma unroll
            for (int mt = 0; mt < 4; ++mt) {
                #pragma unroll
                for (int r = 0; r < 4; ++r) {
                    int row = mg * 64 + mt * 16 + quad * 4 + r;
                    float pre = bf2f(PREu[row * 136 + col]);
                    float x = acc[mt][nt][r] + pre + b1c[nt];
                    float p = x * __builtin_amdgcn_rcpf(1.0f + __expf(-x));
                    Ps[row * 136 + col] = f2bf(p);
                }
            }
        }
    }
    __syncthreads();

    // ---- layer 2: [128x128] @ [128x128] ----
    f32x4 acc2[4][2];
    #pragma unroll
    for (int mt = 0; mt < 4; ++mt)
        #pragma unroll
        for (int nt = 0; nt < 2; ++nt) acc2[mt][nt] = (f32x4){0.f, 0.f, 0.f, 0.f};

    #pragma unroll
    for (int kk = 0; kk < 4; ++kk) {
        int ko = kk * 32 + quad * 8;
        short8 a[4];
        #pragma unroll
        for (int mt = 0; mt < 4; ++mt)
            a[mt] = *(const short8*)(Ps + (mg * 64 + mt * 16 + l15) * 136 + ko);
        #pragma unroll
        for (int nt = 0; nt < 2; ++nt) {
            int n = nsl * 32 + nt * 16 + l15;
            short8 b = *(const short8*)(W2t + n * HID + ko);
            #pragma unroll
            for (int mt = 0; mt < 4; ++mt)
                acc2[mt][nt] = __builtin_amdgcn_mfma_f32_16x16x32_bf16(a[mt], b, acc2[mt][nt], 0, 0, 0);
        }
    }
    __syncthreads();   // Ps reads done before UfT overwrites

    // ---- two 64-row halves: transposed fp32 buffer + merged scatter ----
    float b2c[2] = { b2[nsl * 32 + l15], b2[nsl * 32 + 16 + l15] };
    #pragma unroll
    for (int h = 0; h < 2; ++h) {
        if (mg == h) {
            #pragma unroll
            for (int nt = 0; nt < 2; ++nt) {
                int col = nsl * 32 + nt * 16 + l15;
                #pragma unroll
                for (int mt = 0; mt < 4; ++mt) {
                    f32x4 v;
                    #pragma unroll
                    for (int r = 0; r < 4; ++r) v[r] = acc2[mt][nt][r] + b2c[nt];
                    *(f32x4*)(UfT + col * 68 + mt * 16 + quad * 4) = v;
                }
            }
        }
        __syncthreads();
        {
            int col = tid & 127;
            int seg = tid >> 7;            // 4 segments x 16 rows
            int rb  = h * 64 + seg * 16;
            const float* cp = UfT + col * 68 + seg * 16;
            f32x4 vv[4];
            #pragma unroll
            for (int j = 0; j < 4; ++j) vv[j] = *(const f32x4*)(cp + j * 4);
            int rnode = dn_sh[rb];
            float run = 0.0f;
            #pragma unroll
            for (int i = 0; i < 16; ++i) {
                int node = dn_sh[rb + i];
                float v = vv[i >> 2][i & 3];
                if (node != rnode) {
                    atomicAdd(upd + (size_t)rnode * HID + col, run);
                    rnode = node;
                    run = v;
                } else {
                    run += v;
                }
            }
            atomicAdd(upd + (size_t)rnode * HID + col, run);
        }
        __syncthreads();
    }
}

// ---- normalize by degree + @Wo + bo (MFMA), in place on d_out ----
__launch_bounds__(256, 4)
__global__ void out_kernel(float* __restrict__ out,
                           const int* __restrict__ counts,
                           const short* __restrict__ Wot,
                           const float* __restrict__ bo) {
    __shared__ short A2[64 * 136];

    const int tid  = threadIdx.x;
    const int wave = tid >> 6;
    const int lane = tid & 63;
    const int quad = lane >> 4;
    const int l15  = lane & 15;
    const int n0   = blockIdx.x * 64;

    {
        int row = tid >> 2, pt = tid & 3;
        int node = n0 + row;
        if (node < NN) {
            float inv = 1.0f / fmaxf((float)counts[node], 1.0f);
            const float4* p = (const float4*)(out + (size_t)node * HID + pt * 32);
            #pragma unroll
            for (int j = 0; j < 4; ++j) {
                float4 w0 = p[j * 2], w1 = p[j * 2 + 1];
                short8 o;
                o[0] = f2bf(w0.x * inv); o[1] = f2bf(w0.y * inv);
                o[2] = f2bf(w0.z * inv); o[3] = f2bf(w0.w * inv);
                o[4] = f2bf(w1.x * inv); o[5] = f2bf(w1.y * inv);
                o[6] = f2bf(w1.z * inv); o[7] = f2bf(w1.w * inv);
                *(short8*)(A2 + row * 136 + pt * 32 + j * 8) = o;
            }
        } else {
            short8 z = (short8){0, 0, 0, 0, 0, 0, 0, 0};
            #pragma unroll
            for (int j = 0; j < 4; ++j)
                *(short8*)(A2 + row * 136 + pt * 32 + j * 8) = z;
        }
    }
    __syncthreads();

    f32x4 acc[4][2];
    #pragma unroll
    for (int mt = 0; mt < 4; ++mt)
        #pragma unroll
        for (int nt = 0; nt < 2; ++nt) acc[mt][nt] = (f32x4){0.f, 0.f, 0.f, 0.f};

    #pragma unroll
    for (int kk = 0; kk < 4; ++kk) {
        int ko = kk * 32 + quad * 8;
        short8 a[4];
        #pragma unroll
        for (int mt = 0; mt < 4; ++mt)
            a[mt] = *(const short8*)(A2 + (mt * 16 + l15) * 136 + ko);
        #pragma unroll
        for (int nt = 0; nt < 2; ++nt) {
            int n = wave * 32 + nt * 16 + l15;
            short8 b = *(const short8*)(Wot + n * HID + ko);
            #pragma unroll
            for (int mt = 0; mt < 4; ++mt)
                acc[mt][nt] = __builtin_amdgcn_mfma_f32_16x16x32_bf16(a[mt], b, acc[mt][nt], 0, 0, 0);
        }
    }
    __syncthreads();

    #pragma unroll
    for (int nt = 0; nt < 2; ++nt) {
        int col = wave * 32 + nt * 16 + l15;
        float bias = bo[col];
        #pragma unroll
        for (int mt = 0; mt < 4; ++mt) {
            #pragma unroll
            for (int r = 0; r < 4; ++r) {
                int row = mt * 16 + quad * 4 + r;
                int node = n0 + row;
                if (node < NN)
                    out[(size_t)node * HID + col] = acc[mt][nt][r] + bias;
            }
        }
    }
}

extern "C" void kernel_launch(void* const* d_in, const int* in_sizes, int n_in,
                              void* d_out, int out_size, void* d_ws, size_t ws_size,
                              hipStream_t stream) {
    const float* nf  = (const float*)d_in[0];
    const float* pos = (const float*)d_in[1];
    const int*   ei  = (const int*)d_in[2];
    const float* W1  = (const float*)d_in[3];
    const float* b1  = (const float*)d_in[4];
    const float* W2  = (const float*)d_in[5];
    const float* b2  = (const float*)d_in[6];
    const float* Wo  = (const float*)d_in[7];
    const float* bo  = (const float*)d_in[8];
    float* out = (float*)d_out;

    char* ws = (char*)d_ws;
    short* W1aT     = (short*)(ws);                 //     32,768
    short* W1bT     = (short*)(ws + 32768);         //     32,768
    short* W1cT     = (short*)(ws + 65536);         //      8,192
    short* W2t      = (short*)(ws + 73728);         //     32,768
    short* Wot      = (short*)(ws + 106496);        //     32,768
    int*   counts   = (int*)(ws + 139264);          //    200,704
    int*   cur      = (int*)(ws + 339968);          //    200,704
    int*   blockSum = (int*)(ws + 540672);          //      1,024
    int*   perm     = (int*)(ws + 541696);          //  3,200,000
    short* Sg       = (short*)(ws + 3741696);       // 12,800,000
    short* Dg       = (short*)(ws + 16541696);      // 12,800,000  -> total 29,341,696
    int*   scanEx   = (int*)Sg;   // aliased: dead before sd_kernel writes Sg

    (void)hipMemsetAsync(out, 0, (size_t)NN * HID * sizeof(float), stream);
    (void)hipMemsetAsync(counts, 0, 200704, stream);

    fused_prep<<<3397, 256, 0, stream>>>(ei + NE, counts, W1, W2, Wo,
                                         W1aT, W1bT, W1cT, W2t, Wot);
    k_scan1<<<SCAN_B, 256, 0, stream>>>(counts, scanEx, blockSum);
    k_scan23<<<SCAN_B, 256, 0, stream>>>(scanEx, blockSum, cur);
    k_permute<<<3125, 256, 0, stream>>>(ei + NE, cur, perm);
    sd_kernel<<<(NN + 63) / 64, 256, 0, stream>>>(nf, W1aT, W1bT, Sg, Dg);
    edge_kernel<<<NE / 128, 512, 0, stream>>>(Sg, Dg, pos, perm, ei, ei + NE,
                                              W1cT, b1, W2t, b2, out);
    out_kernel<<<(NN + 63) / 64, 256, 0, stream>>>(out, counts, Wot, bo);
}

// Round 9
// 327.061 us; speedup vs baseline: 1.5065x; 1.0160x over previous
//
#include <hip/hip_runtime.h>
#include <hip/hip_bf16.h>

#define NN 50000
#define NE 800000
#define HID 128
#define NB 32
#define SCAN_B 196   // 196*256 = 50176 >= NN

typedef short short8 __attribute__((ext_vector_type(8)));
typedef float f32x4 __attribute__((ext_vector_type(4)));

static __device__ __forceinline__ short f2bf(float x) {
    union { __hip_bfloat16 h; short s; } r;
    r.h = __float2bfloat16(x);       // HW RNE cvt
    return r.s;
}
static __device__ __forceinline__ float bf2f(unsigned short s) {
    return __uint_as_float(((unsigned int)s) << 16);
}
// packed bf16 add (HW packed add on gfx950)
static __device__ __forceinline__ unsigned int addpack(unsigned int a, unsigned int b) {
    union { unsigned int u; __hip_bfloat162 h; } x, y, r;
    x.u = a; y.u = b;
    r.h = __hadd2(x.h, y.h);
    return r.u;
}

// ---- prep: dst histogram (blocks < 3125) + weight transposes ----
__global__ void fused_prep(const int* __restrict__ dstI, int* __restrict__ counts,
                           const float* __restrict__ W1, const float* __restrict__ W2,
                           const float* __restrict__ Wo,
                           short* __restrict__ W1aT, short* __restrict__ W1bT,
                           short* __restrict__ W1cT, short* __restrict__ W2t,
                           short* __restrict__ Wot) {
    int b = blockIdx.x;
    if (b < 3125) {
        int e = b * 256 + threadIdx.x;
        atomicAdd(&counts[dstI[e]], 1);
    } else {
        int t = (b - 3125) * 256 + threadIdx.x;   // 0..69631
        if (t < 16384) {
            int n = t >> 7, k = t & 127;
            W1aT[t] = f2bf(W1[k * HID + n]);
        } else if ((t -= 16384) < 16384) {
            int n = t >> 7, k = t & 127;
            W1bT[t] = f2bf(W1[(k + 128) * HID + n]);
        } else if ((t -= 16384) < 4096) {
            int n = t >> 5, k = t & 31;
            W1cT[t] = f2bf(W1[(k + 256) * HID + n]);
        } else if ((t -= 4096) < 16384) {
            int n = t >> 7, k = t & 127;
            W2t[t] = f2bf(W2[k * HID + n]);
        } else if ((t -= 16384) < 16384) {
            int n = t >> 7, k = t & 127;
            Wot[t] = f2bf(Wo[k * HID + n]);
        }
    }
}

// ---- scan stage 1 ----
__global__ void k_scan1(const int* __restrict__ counts, int* __restrict__ scanEx,
                        int* __restrict__ blockSum) {
    __shared__ int s[256];
    int t = threadIdx.x, idx = blockIdx.x * 256 + t;
    int v = counts[idx];   // counts sized 50176, zeroed
    s[t] = v; __syncthreads();
    #pragma unroll
    for (int off = 1; off < 256; off <<= 1) {
        int x = (t >= off) ? s[t - off] : 0;
        __syncthreads();
        s[t] += x;
        __syncthreads();
    }
    scanEx[idx] = s[t] - v;
    if (t == 255) blockSum[blockIdx.x] = s[255];
}

// ---- scan stage 2+3 fused: cur = scanEx + sum(blockSum[0..b)) ----
__global__ void k_scan23(const int* __restrict__ scanEx, const int* __restrict__ blockSum,
                         int* __restrict__ cur) {
    __shared__ int s[256];
    int t = threadIdx.x, b = blockIdx.x;
    s[t] = (t < b) ? blockSum[t] : 0;
    __syncthreads();
    #pragma unroll
    for (int off = 128; off > 0; off >>= 1) {
        if (t < off) s[t] += s[t + off];
        __syncthreads();
    }
    int idx = b * 256 + t;
    cur[idx] = scanEx[idx] + s[0];
}

// ---- permute edges into dst-sorted order (packed int2) ----
__global__ void k_permute(const int* __restrict__ src, const int* __restrict__ dst,
                          int* __restrict__ cur, int2* __restrict__ edgeS) {
    int e = blockIdx.x * 256 + threadIdx.x;
    int s = src[e];
    int d = dst[e];
    int r = atomicAdd(&cur[d], 1);
    edgeS[r] = make_int2(s, d);
}

// ---- per-node precompute: S = nf@W1a, D = nf@W1b (bf16 out) ----
__global__ void sd_kernel(const float* __restrict__ nf,
                          const short* __restrict__ W1aT, const short* __restrict__ W1bT,
                          short* __restrict__ Sg, short* __restrict__ Dg) {
    __shared__ short As[64 * 136];
    const int tid  = threadIdx.x;
    const int wave = tid >> 6;
    const int lane = tid & 63;
    const int quad = lane >> 4;
    const int l15  = lane & 15;
    const int n0   = blockIdx.x * 64;

    {
        int row = tid >> 2, pt = tid & 3;
        int node = min(n0 + row, NN - 1);
        const float4* p = (const float4*)(nf + (size_t)node * HID + pt * 32);
        #pragma unroll
        for (int j = 0; j < 4; ++j) {
            float4 w0 = p[j * 2], w1 = p[j * 2 + 1];
            short8 o;
            o[0] = f2bf(w0.x); o[1] = f2bf(w0.y); o[2] = f2bf(w0.z); o[3] = f2bf(w0.w);
            o[4] = f2bf(w1.x); o[5] = f2bf(w1.y); o[6] = f2bf(w1.z); o[7] = f2bf(w1.w);
            *(short8*)(As + row * 136 + pt * 32 + j * 8) = o;
        }
    }
    __syncthreads();

    f32x4 aS[4][2], aD[4][2];
    #pragma unroll
    for (int mt = 0; mt < 4; ++mt)
        #pragma unroll
        for (int nt = 0; nt < 2; ++nt) {
            aS[mt][nt] = (f32x4){0.f, 0.f, 0.f, 0.f};
            aD[mt][nt] = (f32x4){0.f, 0.f, 0.f, 0.f};
        }

    #pragma unroll
    for (int kk = 0; kk < 4; ++kk) {
        int ko = kk * 32 + quad * 8;
        short8 a[4];
        #pragma unroll
        for (int mt = 0; mt < 4; ++mt)
            a[mt] = *(const short8*)(As + (mt * 16 + l15) * 136 + ko);
        #pragma unroll
        for (int nt = 0; nt < 2; ++nt) {
            int n = wave * 32 + nt * 16 + l15;
            short8 bS = *(const short8*)(W1aT + n * HID + ko);
            short8 bD = *(const short8*)(W1bT + n * HID + ko);
            #pragma unroll
            for (int mt = 0; mt < 4; ++mt) {
                aS[mt][nt] = __builtin_amdgcn_mfma_f32_16x16x32_bf16(a[mt], bS, aS[mt][nt], 0, 0, 0);
                aD[mt][nt] = __builtin_amdgcn_mfma_f32_16x16x32_bf16(a[mt], bD, aD[mt][nt], 0, 0, 0);
            }
        }
    }

    #pragma unroll
    for (int nt = 0; nt < 2; ++nt) {
        int col = wave * 32 + nt * 16 + l15;
        #pragma unroll
        for (int mt = 0; mt < 4; ++mt) {
            #pragma unroll
            for (int r = 0; r < 4; ++r) {
                int node = n0 + mt * 16 + quad * 4 + r;
                if (node < NN) {
                    Sg[(size_t)node * HID + col] = f2bf(aS[mt][nt][r]);
                    Dg[(size_t)node * HID + col] = f2bf(aD[mt][nt][r]);
                }
            }
        }
    }
}

// ---- fused edge MLP + tile-merged scatter (edges sorted by dst) ----
// 128 edges/block, 512 threads. Layer1 = rbf@W1c (K=32) + gathered PRE=S[src]+D[dst].
__launch_bounds__(512, 6)
__global__ void edge_kernel(const short* __restrict__ Sg,
                            const short* __restrict__ Dg,
                            const float* __restrict__ pos,
                            const int2* __restrict__ edgeS,
                            const short* __restrict__ W1cT,
                            const float* __restrict__ b1,
                            const short* __restrict__ W2t,
                            const float* __restrict__ b2,
                            float* __restrict__ upd) {
    __shared__ char buf[49152];
    __shared__ int  dn_sh[128];
    short* PRE = (short*)buf;              // [128][136] bf16: S[src]+D[dst]
    short* R   = (short*)(buf + 34816);    // [128][56]  bf16 rbf
    short* Ps  = (short*)buf;              // [128][136] (in-place after PRE consumed)
    float* UfT = (float*)buf;              // [128 cols][68] fp32, one 64-row half

    const int tid  = threadIdx.x;
    const int wave = tid >> 6;
    const int lane = tid & 63;
    const int quad = lane >> 4;
    const int l15  = lane & 15;
    const int mg   = wave >> 2;       // row half: [mg*64, mg*64+64)
    const int nsl  = wave & 3;        // col slice: [nsl*32, nsl*32+32)
    const int e0   = blockIdx.x * 128;

    // ---- stage: PRE = S[src]+D[dst] (packed bf16 HW add), RBF tile, dst ids ----
    {
        int es = tid >> 2, pt = tid & 3;
        int2 sd = edgeS[e0 + es];
        int s = sd.x, d = sd.y;
        const int4* sp = (const int4*)(Sg + (size_t)s * HID + pt * 32);
        const int4* dp = (const int4*)(Dg + (size_t)d * HID + pt * 32);
        int4* op = (int4*)(PRE + es * 136 + pt * 32);
        #pragma unroll
        for (int j = 0; j < 4; ++j) {
            int4 a = sp[j], b = dp[j];
            int4 o;
            o.x = addpack(a.x, b.x);
            o.y = addpack(a.y, b.y);
            o.z = addpack(a.z, b.z);
            o.w = addpack(a.w, b.w);
            op[j] = o;
        }
        if (pt == 0) dn_sh[es] = d;
        float dx = pos[d * 3 + 0] - pos[s * 3 + 0];
        float dy = pos[d * 3 + 1] - pos[s * 3 + 1];
        float dz = pos[d * 3 + 2] - pos[s * 3 + 2];
        float dd = fminf(sqrtf(dx * dx + dy * dy + dz * dz), 5.0f);
        const float step  = 5.0f / 31.0f;
        const float width = 0.5f * (step + 0.01f);
        const float coef  = -0.5f / (width * width);
        short8 r;
        #pragma unroll
        for (int j = 0; j < 8; ++j) {
            float c = step * (float)(pt * 8 + j);
            float t = dd - c;
            r[j] = f2bf(__expf(coef * t * t));
        }
        *(short8*)(R + es * 56 + pt * 8) = r;
    }
    __syncthreads();

    // ---- layer 1: rbf [128x32] @ W1c [32x128], single K-step ----
    f32x4 acc[4][2];
    #pragma unroll
    for (int mt = 0; mt < 4; ++mt)
        #pragma unroll
        for (int nt = 0; nt < 2; ++nt) acc[mt][nt] = (f32x4){0.f, 0.f, 0.f, 0.f};
    {
        int ko = quad * 8;
        short8 a[4];
        #pragma unroll
        for (int mt = 0; mt < 4; ++mt)
            a[mt] = *(const short8*)(R + (mg * 64 + mt * 16 + l15) * 56 + ko);
        #pragma unroll
        for (int nt = 0; nt < 2; ++nt) {
            int n = nsl * 32 + nt * 16 + l15;
            short8 b = *(const short8*)(W1cT + n * NB + ko);
            #pragma unroll
            for (int mt = 0; mt < 4; ++mt)
                acc[mt][nt] = __builtin_amdgcn_mfma_f32_16x16x32_bf16(a[mt], b, acc[mt][nt], 0, 0, 0);
        }
    }

    // ---- + PRE + b1, SiLU -> Ps in place ----
    {
        float b1c[2] = { b1[nsl * 32 + l15], b1[nsl * 32 + 16 + l15] };
        const unsigned short* PREu = (const unsigned short*)PRE;
        #pragma unroll
        for (int nt = 0; nt < 2; ++nt) {
            int col = nsl * 32 + nt * 16 + l15;
            #pragma unroll
            for (int mt = 0; mt < 4; ++mt) {
                #pragma unroll
                for (int r = 0; r < 4; ++r) {
                    int row = mg * 64 + mt * 16 + quad * 4 + r;
                    float pre = bf2f(PREu[row * 136 + col]);
                    float x = acc[mt][nt][r] + pre + b1c[nt];
                    float p = x * __builtin_amdgcn_rcpf(1.0f + __expf(-x));
                    Ps[row * 136 + col] = f2bf(p);
                }
            }
        }
    }
    __syncthreads();

    // ---- layer 2: [128x128] @ [128x128] ----
    f32x4 acc2[4][2];
    #pragma unroll
    for (int mt = 0; mt < 4; ++mt)
        #pragma unroll
        for (int nt = 0; nt < 2; ++nt) acc2[mt][nt] = (f32x4){0.f, 0.f, 0.f, 0.f};

    #pragma unroll
    for (int kk = 0; kk < 4; ++kk) {
        int ko = kk * 32 + quad * 8;
        short8 a[4];
        #pragma unroll
        for (int mt = 0; mt < 4; ++mt)
            a[mt] = *(const short8*)(Ps + (mg * 64 + mt * 16 + l15) * 136 + ko);
        #pragma unroll
        for (int nt = 0; nt < 2; ++nt) {
            int n = nsl * 32 + nt * 16 + l15;
            short8 b = *(const short8*)(W2t + n * HID + ko);
            #pragma unroll
            for (int mt = 0; mt < 4; ++mt)
                acc2[mt][nt] = __builtin_amdgcn_mfma_f32_16x16x32_bf16(a[mt], b, acc2[mt][nt], 0, 0, 0);
        }
    }
    __syncthreads();   // Ps reads done before UfT overwrites

    // ---- two 64-row halves: transposed fp32 buffer + merged scatter ----
    float b2c[2] = { b2[nsl * 32 + l15], b2[nsl * 32 + 16 + l15] };
    #pragma unroll
    for (int h = 0; h < 2; ++h) {
        if (mg == h) {
            #pragma unroll
            for (int nt = 0; nt < 2; ++nt) {
                int col = nsl * 32 + nt * 16 + l15;
                #pragma unroll
                for (int mt = 0; mt < 4; ++mt) {
                    f32x4 v;
                    #pragma unroll
                    for (int r = 0; r < 4; ++r) v[r] = acc2[mt][nt][r] + b2c[nt];
                    *(f32x4*)(UfT + col * 68 + mt * 16 + quad * 4) = v;
                }
            }
        }
        __syncthreads();
        {
            int col = tid & 127;
            int seg = tid >> 7;            // 4 segments x 16 rows
            int rb  = h * 64 + seg * 16;
            const float* cp = UfT + col * 68 + seg * 16;
            f32x4 vv[4];
            #pragma unroll
            for (int j = 0; j < 4; ++j) vv[j] = *(const f32x4*)(cp + j * 4);
            int rnode = dn_sh[rb];
            float run = 0.0f;
            #pragma unroll
            for (int i = 0; i < 16; ++i) {
                int node = dn_sh[rb + i];
                float v = vv[i >> 2][i & 3];
                if (node != rnode) {
                    atomicAdd(upd + (size_t)rnode * HID + col, run);
                    rnode = node;
                    run = v;
                } else {
                    run += v;
                }
            }
            atomicAdd(upd + (size_t)rnode * HID + col, run);
        }
        __syncthreads();
    }
}

// ---- normalize by degree + @Wo + bo (MFMA), in place on d_out ----
__launch_bounds__(256, 4)
__global__ void out_kernel(float* __restrict__ out,
                           const int* __restrict__ counts,
                           const short* __restrict__ Wot,
                           const float* __restrict__ bo) {
    __shared__ short A2[64 * 136];

    const int tid  = threadIdx.x;
    const int wave = tid >> 6;
    const int lane = tid & 63;
    const int quad = lane >> 4;
    const int l15  = lane & 15;
    const int n0   = blockIdx.x * 64;

    {
        int row = tid >> 2, pt = tid & 3;
        int node = n0 + row;
        if (node < NN) {
            float inv = 1.0f / fmaxf((float)counts[node], 1.0f);
            const float4* p = (const float4*)(out + (size_t)node * HID + pt * 32);
            #pragma unroll
            for (int j = 0; j < 4; ++j) {
                float4 w0 = p[j * 2], w1 = p[j * 2 + 1];
                short8 o;
                o[0] = f2bf(w0.x * inv); o[1] = f2bf(w0.y * inv);
                o[2] = f2bf(w0.z * inv); o[3] = f2bf(w0.w * inv);
                o[4] = f2bf(w1.x * inv); o[5] = f2bf(w1.y * inv);
                o[6] = f2bf(w1.z * inv); o[7] = f2bf(w1.w * inv);
                *(short8*)(A2 + row * 136 + pt * 32 + j * 8) = o;
            }
        } else {
            short8 z = (short8){0, 0, 0, 0, 0, 0, 0, 0};
            #pragma unroll
            for (int j = 0; j < 4; ++j)
                *(short8*)(A2 + row * 136 + pt * 32 + j * 8) = z;
        }
    }
    __syncthreads();

    f32x4 acc[4][2];
    #pragma unroll
    for (int mt = 0; mt < 4; ++mt)
        #pragma unroll
        for (int nt = 0; nt < 2; ++nt) acc[mt][nt] = (f32x4){0.f, 0.f, 0.f, 0.f};

    #pragma unroll
    for (int kk = 0; kk < 4; ++kk) {
        int ko = kk * 32 + quad * 8;
        short8 a[4];
        #pragma unroll
        for (int mt = 0; mt < 4; ++mt)
            a[mt] = *(const short8*)(A2 + (mt * 16 + l15) * 136 + ko);
        #pragma unroll
        for (int nt = 0; nt < 2; ++nt) {
            int n = wave * 32 + nt * 16 + l15;
            short8 b = *(const short8*)(Wot + n * HID + ko);
            #pragma unroll
            for (int mt = 0; mt < 4; ++mt)
                acc[mt][nt] = __builtin_amdgcn_mfma_f32_16x16x32_bf16(a[mt], b, acc[mt][nt], 0, 0, 0);
        }
    }
    __syncthreads();

    #pragma unroll
    for (int nt = 0; nt < 2; ++nt) {
        int col = wave * 32 + nt * 16 + l15;
        float bias = bo[col];
        #pragma unroll
        for (int mt = 0; mt < 4; ++mt) {
            #pragma unroll
            for (int r = 0; r < 4; ++r) {
                int row = mt * 16 + quad * 4 + r;
                int node = n0 + row;
                if (node < NN)
                    out[(size_t)node * HID + col] = acc[mt][nt][r] + bias;
            }
        }
    }
}

extern "C" void kernel_launch(void* const* d_in, const int* in_sizes, int n_in,
                              void* d_out, int out_size, void* d_ws, size_t ws_size,
                              hipStream_t stream) {
    const float* nf  = (const float*)d_in[0];
    const float* pos = (const float*)d_in[1];
    const int*   ei  = (const int*)d_in[2];
    const float* W1  = (const float*)d_in[3];
    const float* b1  = (const float*)d_in[4];
    const float* W2  = (const float*)d_in[5];
    const float* b2  = (const float*)d_in[6];
    const float* Wo  = (const float*)d_in[7];
    const float* bo  = (const float*)d_in[8];
    float* out = (float*)d_out;

    char* ws = (char*)d_ws;
    short* W1aT     = (short*)(ws);                 //     32,768
    short* W1bT     = (short*)(ws + 32768);         //     32,768
    short* W1cT     = (short*)(ws + 65536);         //      8,192
    short* W2t      = (short*)(ws + 73728);         //     32,768
    short* Wot      = (short*)(ws + 106496);        //     32,768
    int*   counts   = (int*)(ws + 139264);          //    200,704
    int*   cur      = (int*)(ws + 339968);          //    200,704
    int*   blockSum = (int*)(ws + 540672);          //      1,024
    int2*  edgeS    = (int2*)(ws + 541696);         //  6,400,000
    short* Sg       = (short*)(ws + 6941696);       // 12,800,000
    short* Dg       = (short*)(ws + 19741696);      // 12,800,000  -> total 32,541,696
    int*   scanEx   = (int*)Sg;   // aliased: dead before sd_kernel writes Sg

    (void)hipMemsetAsync(out, 0, (size_t)NN * HID * sizeof(float), stream);
    (void)hipMemsetAsync(counts, 0, 200704, stream);

    fused_prep<<<3397, 256, 0, stream>>>(ei + NE, counts, W1, W2, Wo,
                                         W1aT, W1bT, W1cT, W2t, Wot);
    k_scan1<<<SCAN_B, 256, 0, stream>>>(counts, scanEx, blockSum);
    k_scan23<<<SCAN_B, 256, 0, stream>>>(scanEx, blockSum, cur);
    k_permute<<<3125, 256, 0, stream>>>(ei, ei + NE, cur, edgeS);
    sd_kernel<<<(NN + 63) / 64, 256, 0, stream>>>(nf, W1aT, W1bT, Sg, Dg);
    edge_kernel<<<NE / 128, 512, 0, stream>>>(Sg, Dg, pos, edgeS,
                                              W1cT, b1, W2t, b2, out);
    out_kernel<<<(NN + 63) / 64, 256, 0, stream>>>(out, counts, Wot, bo);
}

// Round 10
// 325.868 us; speedup vs baseline: 1.5121x; 1.0037x over previous
//
#include <hip/hip_runtime.h>
#include <hip/hip_bf16.h>

#define NN 50000
#define NE 800000
#define HID 128
#define NB 32
#define SCAN_B 196   // 196*256 = 50176 >= NN
#define SD_B 782     // sd tiles: ceil(50000/64)

typedef short short8 __attribute__((ext_vector_type(8)));
typedef float f32x4 __attribute__((ext_vector_type(4)));

static __device__ __forceinline__ short f2bf(float x) {
    union { __hip_bfloat16 h; short s; } r;
    r.h = __float2bfloat16(x);       // HW RNE cvt
    return r.s;
}
static __device__ __forceinline__ float bf2f(unsigned short s) {
    return __uint_as_float(((unsigned int)s) << 16);
}
// packed bf16 add (HW packed add on gfx950)
static __device__ __forceinline__ unsigned int addpack(unsigned int a, unsigned int b) {
    union { unsigned int u; __hip_bfloat162 h; } x, y, r;
    x.u = a; y.u = b;
    r.h = __hadd2(x.h, y.h);
    return r.u;
}

// ---- prep: zero out + dst histogram (blocks < 3125) + weight transposes ----
__global__ void fused_prep(const int* __restrict__ dstI, int* __restrict__ counts,
                           const float* __restrict__ W1, const float* __restrict__ W2,
                           const float* __restrict__ Wo,
                           short* __restrict__ W1aT, short* __restrict__ W1bT,
                           short* __restrict__ W1cT, short* __restrict__ W2t,
                           short* __restrict__ Wot,
                           float* __restrict__ out) {
    int b = blockIdx.x;
    // grid-stride zero of out (all blocks participate)
    {
        int gtid = b * 256 + threadIdx.x;
        const int nthr = 3397 * 256;
        float4 z = make_float4(0.f, 0.f, 0.f, 0.f);
        for (int i = gtid; i < NN * HID / 4; i += nthr)
            ((float4*)out)[i] = z;
    }
    if (b < 3125) {
        int e = b * 256 + threadIdx.x;
        atomicAdd(&counts[dstI[e]], 1);
    } else {
        int t = (b - 3125) * 256 + threadIdx.x;   // 0..69631
        if (t < 16384) {
            int n = t >> 7, k = t & 127;
            W1aT[t] = f2bf(W1[k * HID + n]);
        } else if ((t -= 16384) < 16384) {
            int n = t >> 7, k = t & 127;
            W1bT[t] = f2bf(W1[(k + 128) * HID + n]);
        } else if ((t -= 16384) < 4096) {
            int n = t >> 5, k = t & 31;
            W1cT[t] = f2bf(W1[(k + 256) * HID + n]);
        } else if ((t -= 4096) < 16384) {
            int n = t >> 7, k = t & 127;
            W2t[t] = f2bf(W2[k * HID + n]);
        } else if ((t -= 16384) < 16384) {
            int n = t >> 7, k = t & 127;
            Wot[t] = f2bf(Wo[k * HID + n]);
        }
    }
}

// ---- scan stage 1 ----
__global__ void k_scan1(const int* __restrict__ counts, int* __restrict__ scanEx,
                        int* __restrict__ blockSum) {
    __shared__ int s[256];
    int t = threadIdx.x, idx = blockIdx.x * 256 + t;
    int v = counts[idx];   // counts sized 50176, zeroed
    s[t] = v; __syncthreads();
    #pragma unroll
    for (int off = 1; off < 256; off <<= 1) {
        int x = (t >= off) ? s[t - off] : 0;
        __syncthreads();
        s[t] += x;
        __syncthreads();
    }
    scanEx[idx] = s[t] - v;
    if (t == 255) blockSum[blockIdx.x] = s[255];
}

// ---- scan stage 2+3 fused: cur = scanEx + sum(blockSum[0..b)) ----
__global__ void k_scan23(const int* __restrict__ scanEx, const int* __restrict__ blockSum,
                         int* __restrict__ cur) {
    __shared__ int s[256];
    int t = threadIdx.x, b = blockIdx.x;
    s[t] = (t < b) ? blockSum[t] : 0;
    __syncthreads();
    #pragma unroll
    for (int off = 128; off > 0; off >>= 1) {
        if (t < off) s[t] += s[t + off];
        __syncthreads();
    }
    int idx = b * 256 + t;
    cur[idx] = scanEx[idx] + s[0];
}

// ---- fused: sd GEMM (blocks < SD_B) + edge permute (blocks >= SD_B) ----
// Roles are independent after scan23; MFMA-bound sd and atomic-bound permute
// co-schedule on different pipes (m114-style overlap).
__launch_bounds__(256, 4)
__global__ void perm_sd(const float* __restrict__ nf,
                        const short* __restrict__ W1aT, const short* __restrict__ W1bT,
                        short* __restrict__ Sg, short* __restrict__ Dg,
                        const int* __restrict__ src, const int* __restrict__ dst,
                        int* __restrict__ cur, int2* __restrict__ edgeS) {
    __shared__ short As[64 * 136];
    const int tid = threadIdx.x;

    if (blockIdx.x >= SD_B) {
        // ---- permute role ----
        int e = (blockIdx.x - SD_B) * 256 + tid;
        int s = src[e];
        int d = dst[e];
        int r = atomicAdd(&cur[d], 1);
        edgeS[r] = make_int2(s, d);
        return;
    }

    // ---- sd role: S = nf@W1a, D = nf@W1b (bf16 out, coalesced via LDS repack) ----
    const int wave = tid >> 6;
    const int lane = tid & 63;
    const int quad = lane >> 4;
    const int l15  = lane & 15;
    const int n0   = blockIdx.x * 64;
    const int row  = tid >> 2, pt = tid & 3;

    {
        int node = min(n0 + row, NN - 1);
        const float4* p = (const float4*)(nf + (size_t)node * HID + pt * 32);
        #pragma unroll
        for (int j = 0; j < 4; ++j) {
            float4 w0 = p[j * 2], w1 = p[j * 2 + 1];
            short8 o;
            o[0] = f2bf(w0.x); o[1] = f2bf(w0.y); o[2] = f2bf(w0.z); o[3] = f2bf(w0.w);
            o[4] = f2bf(w1.x); o[5] = f2bf(w1.y); o[6] = f2bf(w1.z); o[7] = f2bf(w1.w);
            *(short8*)(As + row * 136 + pt * 32 + j * 8) = o;
        }
    }
    __syncthreads();

    f32x4 aS[4][2], aD[4][2];
    #pragma unroll
    for (int mt = 0; mt < 4; ++mt)
        #pragma unroll
        for (int nt = 0; nt < 2; ++nt) {
            aS[mt][nt] = (f32x4){0.f, 0.f, 0.f, 0.f};
            aD[mt][nt] = (f32x4){0.f, 0.f, 0.f, 0.f};
        }

    #pragma unroll
    for (int kk = 0; kk < 4; ++kk) {
        int ko = kk * 32 + quad * 8;
        short8 a[4];
        #pragma unroll
        for (int mt = 0; mt < 4; ++mt)
            a[mt] = *(const short8*)(As + (mt * 16 + l15) * 136 + ko);
        #pragma unroll
        for (int nt = 0; nt < 2; ++nt) {
            int n = wave * 32 + nt * 16 + l15;
            short8 bS = *(const short8*)(W1aT + n * HID + ko);
            short8 bD = *(const short8*)(W1bT + n * HID + ko);
            #pragma unroll
            for (int mt = 0; mt < 4; ++mt) {
                aS[mt][nt] = __builtin_amdgcn_mfma_f32_16x16x32_bf16(a[mt], bS, aS[mt][nt], 0, 0, 0);
                aD[mt][nt] = __builtin_amdgcn_mfma_f32_16x16x32_bf16(a[mt], bD, aD[mt][nt], 0, 0, 0);
            }
        }
    }
    __syncthreads();   // A-frag reads done; reuse As for repack

    // repack S -> coalesced row stores
    #pragma unroll
    for (int nt = 0; nt < 2; ++nt) {
        int col = wave * 32 + nt * 16 + l15;
        #pragma unroll
        for (int mt = 0; mt < 4; ++mt)
            #pragma unroll
            for (int r = 0; r < 4; ++r)
                As[(mt * 16 + quad * 4 + r) * 136 + col] = f2bf(aS[mt][nt][r]);
    }
    __syncthreads();
    if (n0 + row < NN) {
        short8* gp = (short8*)(Sg + (size_t)(n0 + row) * HID + pt * 32);
        #pragma unroll
        for (int j = 0; j < 4; ++j)
            gp[j] = *(const short8*)(As + row * 136 + pt * 32 + j * 8);
    }
    __syncthreads();

    // repack D -> coalesced row stores
    #pragma unroll
    for (int nt = 0; nt < 2; ++nt) {
        int col = wave * 32 + nt * 16 + l15;
        #pragma unroll
        for (int mt = 0; mt < 4; ++mt)
            #pragma unroll
            for (int r = 0; r < 4; ++r)
                As[(mt * 16 + quad * 4 + r) * 136 + col] = f2bf(aD[mt][nt][r]);
    }
    __syncthreads();
    if (n0 + row < NN) {
        short8* gp = (short8*)(Dg + (size_t)(n0 + row) * HID + pt * 32);
        #pragma unroll
        for (int j = 0; j < 4; ++j)
            gp[j] = *(const short8*)(As + row * 136 + pt * 32 + j * 8);
    }
}

// ---- fused edge MLP + tile-merged scatter (edges sorted by dst) ----
// 128 edges/block, 512 threads. Layer1 = rbf@W1c (K=32) + gathered PRE=S[src]+D[dst].
__launch_bounds__(512, 6)
__global__ void edge_kernel(const short* __restrict__ Sg,
                            const short* __restrict__ Dg,
                            const float* __restrict__ pos,
                            const int2* __restrict__ edgeS,
                            const short* __restrict__ W1cT,
                            const float* __restrict__ b1,
                            const short* __restrict__ W2t,
                            const float* __restrict__ b2,
                            float* __restrict__ upd) {
    __shared__ char buf[49152];
    __shared__ int  dn_sh[128];
    short* PRE = (short*)buf;              // [128][136] bf16: S[src]+D[dst]
    short* R   = (short*)(buf + 34816);    // [128][56]  bf16 rbf
    short* Ps  = (short*)buf;              // [128][136] (in-place after PRE consumed)
    float* UfT = (float*)buf;              // [128 cols][68] fp32, one 64-row half

    const int tid  = threadIdx.x;
    const int wave = tid >> 6;
    const int lane = tid & 63;
    const int quad = lane >> 4;
    const int l15  = lane & 15;
    const int mg   = wave >> 2;       // row half: [mg*64, mg*64+64)
    const int nsl  = wave & 3;        // col slice: [nsl*32, nsl*32+32)
    const int e0   = blockIdx.x * 128;

    // ---- stage: PRE = S[src]+D[dst] (packed bf16 HW add), RBF tile, dst ids ----
    {
        int es = tid >> 2, pt = tid & 3;
        int2 sd = edgeS[e0 + es];
        int s = sd.x, d = sd.y;
        const int4* sp = (const int4*)(Sg + (size_t)s * HID + pt * 32);
        const int4* dp = (const int4*)(Dg + (size_t)d * HID + pt * 32);
        int4* op = (int4*)(PRE + es * 136 + pt * 32);
        #pragma unroll
        for (int j = 0; j < 4; ++j) {
            int4 a = sp[j], b = dp[j];
            int4 o;
            o.x = addpack(a.x, b.x);
            o.y = addpack(a.y, b.y);
            o.z = addpack(a.z, b.z);
            o.w = addpack(a.w, b.w);
            op[j] = o;
        }
        if (pt == 0) dn_sh[es] = d;
        float dx = pos[d * 3 + 0] - pos[s * 3 + 0];
        float dy = pos[d * 3 + 1] - pos[s * 3 + 1];
        float dz = pos[d * 3 + 2] - pos[s * 3 + 2];
        float dd = fminf(sqrtf(dx * dx + dy * dy + dz * dz), 5.0f);
        const float step  = 5.0f / 31.0f;
        const float width = 0.5f * (step + 0.01f);
        const float coef  = -0.5f / (width * width);
        short8 r;
        #pragma unroll
        for (int j = 0; j < 8; ++j) {
            float c = step * (float)(pt * 8 + j);
            float t = dd - c;
            r[j] = f2bf(__expf(coef * t * t));
        }
        *(short8*)(R + es * 56 + pt * 8) = r;
    }
    __syncthreads();

    // ---- layer 1: rbf [128x32] @ W1c [32x128], single K-step ----
    f32x4 acc[4][2];
    #pragma unroll
    for (int mt = 0; mt < 4; ++mt)
        #pragma unroll
        for (int nt = 0; nt < 2; ++nt) acc[mt][nt] = (f32x4){0.f, 0.f, 0.f, 0.f};
    {
        int ko = quad * 8;
        short8 a[4];
        #pragma unroll
        for (int mt = 0; mt < 4; ++mt)
            a[mt] = *(const short8*)(R + (mg * 64 + mt * 16 + l15) * 56 + ko);
        #pragma unroll
        for (int nt = 0; nt < 2; ++nt) {
            int n = nsl * 32 + nt * 16 + l15;
            short8 b = *(const short8*)(W1cT + n * NB + ko);
            #pragma unroll
            for (int mt = 0; mt < 4; ++mt)
                acc[mt][nt] = __builtin_amdgcn_mfma_f32_16x16x32_bf16(a[mt], b, acc[mt][nt], 0, 0, 0);
        }
    }

    // ---- + PRE + b1, SiLU -> Ps in place ----
    {
        float b1c[2] = { b1[nsl * 32 + l15], b1[nsl * 32 + 16 + l15] };
        const unsigned short* PREu = (const unsigned short*)PRE;
        #pragma unroll
        for (int nt = 0; nt < 2; ++nt) {
            int col = nsl * 32 + nt * 16 + l15;
            #pragma unroll
            for (int mt = 0; mt < 4; ++mt) {
                #pragma unroll
                for (int r = 0; r < 4; ++r) {
                    int row = mg * 64 + mt * 16 + quad * 4 + r;
                    float pre = bf2f(PREu[row * 136 + col]);
                    float x = acc[mt][nt][r] + pre + b1c[nt];
                    float p = x * __builtin_amdgcn_rcpf(1.0f + __expf(-x));
                    Ps[row * 136 + col] = f2bf(p);
                }
            }
        }
    }
    __syncthreads();

    // ---- layer 2: [128x128] @ [128x128] ----
    f32x4 acc2[4][2];
    #pragma unroll
    for (int mt = 0; mt < 4; ++mt)
        #pragma unroll
        for (int nt = 0; nt < 2; ++nt) acc2[mt][nt] = (f32x4){0.f, 0.f, 0.f, 0.f};

    #pragma unroll
    for (int kk = 0; kk < 4; ++kk) {
        int ko = kk * 32 + quad * 8;
        short8 a[4];
        #pragma unroll
        for (int mt = 0; mt < 4; ++mt)
            a[mt] = *(const short8*)(Ps + (mg * 64 + mt * 16 + l15) * 136 + ko);
        #pragma unroll
        for (int nt = 0; nt < 2; ++nt) {
            int n = nsl * 32 + nt * 16 + l15;
            short8 b = *(const short8*)(W2t + n * HID + ko);
            #pragma unroll
            for (int mt = 0; mt < 4; ++mt)
                acc2[mt][nt] = __builtin_amdgcn_mfma_f32_16x16x32_bf16(a[mt], b, acc2[mt][nt], 0, 0, 0);
        }
    }
    __syncthreads();   // Ps reads done before UfT overwrites

    // ---- two 64-row halves: transposed fp32 buffer + merged scatter ----
    float b2c[2] = { b2[nsl * 32 + l15], b2[nsl * 32 + 16 + l15] };
    #pragma unroll
    for (int h = 0; h < 2; ++h) {
        if (mg == h) {
            #pragma unroll
            for (int nt = 0; nt < 2; ++nt) {
                int col = nsl * 32 + nt * 16 + l15;
                #pragma unroll
                for (int mt = 0; mt < 4; ++mt) {
                    f32x4 v;
                    #pragma unroll
                    for (int r = 0; r < 4; ++r) v[r] = acc2[mt][nt][r] + b2c[nt];
                    *(f32x4*)(UfT + col * 68 + mt * 16 + quad * 4) = v;
                }
            }
        }
        __syncthreads();
        {
            int col = tid & 127;
            int seg = tid >> 7;            // 4 segments x 16 rows
            int rb  = h * 64 + seg * 16;
            const float* cp = UfT + col * 68 + seg * 16;
            f32x4 vv[4];
            #pragma unroll
            for (int j = 0; j < 4; ++j) vv[j] = *(const f32x4*)(cp + j * 4);
            int rnode = dn_sh[rb];
            float run = 0.0f;
            #pragma unroll
            for (int i = 0; i < 16; ++i) {
                int node = dn_sh[rb + i];
                float v = vv[i >> 2][i & 3];
                if (node != rnode) {
                    atomicAdd(upd + (size_t)rnode * HID + col, run);
                    rnode = node;
                    run = v;
                } else {
                    run += v;
                }
            }
            atomicAdd(upd + (size_t)rnode * HID + col, run);
        }
        __syncthreads();
    }
}

// ---- normalize by degree + @Wo + bo (MFMA), in place on d_out ----
__launch_bounds__(256, 4)
__global__ void out_kernel(float* __restrict__ out,
                           const int* __restrict__ counts,
                           const short* __restrict__ Wot,
                           const float* __restrict__ bo) {
    __shared__ short A2[64 * 136];

    const int tid  = threadIdx.x;
    const int wave = tid >> 6;
    const int lane = tid & 63;
    const int quad = lane >> 4;
    const int l15  = lane & 15;
    const int n0   = blockIdx.x * 64;

    {
        int row = tid >> 2, pt = tid & 3;
        int node = n0 + row;
        if (node < NN) {
            float inv = 1.0f / fmaxf((float)counts[node], 1.0f);
            const float4* p = (const float4*)(out + (size_t)node * HID + pt * 32);
            #pragma unroll
            for (int j = 0; j < 4; ++j) {
                float4 w0 = p[j * 2], w1 = p[j * 2 + 1];
                short8 o;
                o[0] = f2bf(w0.x * inv); o[1] = f2bf(w0.y * inv);
                o[2] = f2bf(w0.z * inv); o[3] = f2bf(w0.w * inv);
                o[4] = f2bf(w1.x * inv); o[5] = f2bf(w1.y * inv);
                o[6] = f2bf(w1.z * inv); o[7] = f2bf(w1.w * inv);
                *(short8*)(A2 + row * 136 + pt * 32 + j * 8) = o;
            }
        } else {
            short8 z = (short8){0, 0, 0, 0, 0, 0, 0, 0};
            #pragma unroll
            for (int j = 0; j < 4; ++j)
                *(short8*)(A2 + row * 136 + pt * 32 + j * 8) = z;
        }
    }
    __syncthreads();

    f32x4 acc[4][2];
    #pragma unroll
    for (int mt = 0; mt < 4; ++mt)
        #pragma unroll
        for (int nt = 0; nt < 2; ++nt) acc[mt][nt] = (f32x4){0.f, 0.f, 0.f, 0.f};

    #pragma unroll
    for (int kk = 0; kk < 4; ++kk) {
        int ko = kk * 32 + quad * 8;
        short8 a[4];
        #pragma unroll
        for (int mt = 0; mt < 4; ++mt)
            a[mt] = *(const short8*)(A2 + (mt * 16 + l15) * 136 + ko);
        #pragma unroll
        for (int nt = 0; nt < 2; ++nt) {
            int n = wave * 32 + nt * 16 + l15;
            short8 b = *(const short8*)(Wot + n * HID + ko);
            #pragma unroll
            for (int mt = 0; mt < 4; ++mt)
                acc[mt][nt] = __builtin_amdgcn_mfma_f32_16x16x32_bf16(a[mt], b, acc[mt][nt], 0, 0, 0);
        }
    }
    __syncthreads();

    #pragma unroll
    for (int nt = 0; nt < 2; ++nt) {
        int col = wave * 32 + nt * 16 + l15;
        float bias = bo[col];
        #pragma unroll
        for (int mt = 0; mt < 4; ++mt) {
            #pragma unroll
            for (int r = 0; r < 4; ++r) {
                int row = mt * 16 + quad * 4 + r;
                int node = n0 + row;
                if (node < NN)
                    out[(size_t)node * HID + col] = acc[mt][nt][r] + bias;
            }
        }
    }
}

extern "C" void kernel_launch(void* const* d_in, const int* in_sizes, int n_in,
                              void* d_out, int out_size, void* d_ws, size_t ws_size,
                              hipStream_t stream) {
    const float* nf  = (const float*)d_in[0];
    const float* pos = (const float*)d_in[1];
    const int*   ei  = (const int*)d_in[2];
    const float* W1  = (const float*)d_in[3];
    const float* b1  = (const float*)d_in[4];
    const float* W2  = (const float*)d_in[5];
    const float* b2  = (const float*)d_in[6];
    const float* Wo  = (const float*)d_in[7];
    const float* bo  = (const float*)d_in[8];
    float* out = (float*)d_out;

    char* ws = (char*)d_ws;
    short* W1aT     = (short*)(ws);                 //     32,768
    short* W1bT     = (short*)(ws + 32768);         //     32,768
    short* W1cT     = (short*)(ws + 65536);         //      8,192
    short* W2t      = (short*)(ws + 73728);         //     32,768
    short* Wot      = (short*)(ws + 106496);        //     32,768
    int*   counts   = (int*)(ws + 139264);          //    200,704
    int*   cur      = (int*)(ws + 339968);          //    200,704
    int*   blockSum = (int*)(ws + 540672);          //      1,024
    int2*  edgeS    = (int2*)(ws + 541696);         //  6,400,000
    short* Sg       = (short*)(ws + 6941696);       // 12,800,000
    short* Dg       = (short*)(ws + 19741696);      // 12,800,000  -> total 32,541,696
    int*   scanEx   = (int*)Sg;   // aliased: dead before perm_sd writes Sg

    (void)hipMemsetAsync(counts, 0, 200704, stream);

    fused_prep<<<3397, 256, 0, stream>>>(ei + NE, counts, W1, W2, Wo,
                                         W1aT, W1bT, W1cT, W2t, Wot, out);
    k_scan1<<<SCAN_B, 256, 0, stream>>>(counts, scanEx, blockSum);
    k_scan23<<<SCAN_B, 256, 0, stream>>>(scanEx, blockSum, cur);
    perm_sd<<<SD_B + 3125, 256, 0, stream>>>(nf, W1aT, W1bT, Sg, Dg,
                                             ei, ei + NE, cur, edgeS);
    edge_kernel<<<NE / 128, 512, 0, stream>>>(Sg, Dg, pos, edgeS,
                                              W1cT, b1, W2t, b2, out);
    out_kernel<<<(NN + 63) / 64, 256, 0, stream>>>(out, counts, Wot, bo);
}